// Round 6
// baseline (190.878 us; speedup 1.0000x reference)
//
#include <hip/hip_runtime.h>
#include <hip/hip_bf16.h>

#define B_N     2048
#define IN_N    512
#define SEQ_N   128
#define HID_N   12
#define HP_N    16
#define OUT_N   3
#define CSTF    524   // f32 C row stride (dword stride 524%32 spreads banks)
#define CSTB    520   // bf16 C row stride: 1040B rows, 16B-aligned; quarter-wave
                      // b128 reads land 2 dwords/bank = conflict-free minimum

typedef __attribute__((ext_vector_type(8))) short short8;
typedef __attribute__((ext_vector_type(4))) float f32x4;
typedef unsigned int uint;
typedef unsigned short ushort;

__device__ __forceinline__ float fast_tanh(float x) {
    float e = __builtin_amdgcn_exp2f(x * 2.8853900817779268f);
    return 1.0f - 2.0f * __builtin_amdgcn_rcpf(e + 1.0f);
}

__device__ __forceinline__ ushort f2bf(float f) {   // RNE fp32->bf16
    uint u = __float_as_uint(f);
    u += 0x7fffu + ((u >> 16) & 1u);
    return (ushort)(u >> 16);
}

// DPP quad-broadcast: every lane in a quad gets lane (quad_base + Q)'s value.
template<int Q>
__device__ __forceinline__ float qbcast(float v) {
    return __int_as_float(__builtin_amdgcn_update_dpp(
        0, __float_as_int(v), Q * 0x55, 0xf, 0xf, true));
}

// gather 4 quad values of src into d[0..3]
__device__ __forceinline__ void qgather(float src, float* d) {
    d[0] = qbcast<0>(src);
    d[1] = qbcast<1>(src);
    d[2] = qbcast<2>(src);
    d[3] = qbcast<3>(src);
}

// ---------------------------------------------------------------------------
// k_prep: pack embT (128 s x 512 r) into MFMA A-fragment order (bf16).
// Frag f = t8*16 + ks covers s in [t8*16,+16), r in [ks*32,+32).
// Lane l holds A[m=l&15][k=(l>>4)*8+j] = emb[r0+j][s], uint4-packed.
// ---------------------------------------------------------------------------
__global__ __launch_bounds__(64) void k_prep(
    const float* __restrict__ emb, ushort* __restrict__ embF)
{
    const int f  = blockIdx.x;          // 0..127
    const int l  = threadIdx.x;
    const int t8 = f >> 4, ks = f & 15;
    const int s  = t8 * 16 + (l & 15);
    const int r0 = ks * 32 + (l >> 4) * 8;
    ushort v[8];
    #pragma unroll
    for (int j = 0; j < 8; ++j)
        v[j] = f2bf(emb[(r0 + j) * SEQ_N + s]);
    uint4 o;
    o.x = (uint)v[0] | ((uint)v[1] << 16);
    o.y = (uint)v[2] | ((uint)v[3] << 16);
    o.z = (uint)v[4] | ((uint)v[5] << 16);
    o.w = (uint)v[6] | ((uint)v[7] << 16);
    ((uint4*)embF)[f * 64 + l] = o;
}

// ---------------------------------------------------------------------------
// k_pre v5: 512 blocks x 256 thr, 4 batches per block.
// A-fragments (batch-invariant) live in REGISTERS: wave w owns tiles
// {2w, 2w+1} = 32 frags = 128 VGPR, loaded once from embF.
// Per batch: LDS scatter C_b -> cvt bf16 -> ds_read B-frags -> 32 MFMA.
// No global loads inside the MFMA loop.
// Output preB[b][s][h16] bf16, full 32-B records (pads zeroed).
// ---------------------------------------------------------------------------
__global__ __launch_bounds__(256) void k_pre(
    const int* __restrict__ x, const ushort* __restrict__ embF,
    const float* __restrict__ w_ih_f, ushort* __restrict__ preB)
{
    __shared__ __align__(16) float U[12 * CSTF];   // 25.2 KB, reused as Cb
    __shared__ int xb[IN_N];
    ushort* Cb = (ushort*)U;

    const int t    = threadIdx.x;
    const int w    = t >> 6;
    const int l    = t & 63;
    const int h16  = l & 15;
    const int quad = l >> 4;

    // hoist w_ih_f loads (batch-invariant): thread t covers i = t, t+256
    float wv[2][12];
    #pragma unroll
    for (int k = 0; k < 2; ++k) {
        int i = t + k * 256;
        #pragma unroll
        for (int h = 0; h < 12; ++h) wv[k][h] = w_ih_f[h * IN_N + i];
    }

    // load this wave's A-fragments once (2 tiles x 16 ks)
    const uint4* eF = (const uint4*)embF;
    short8 A[2][16];
    #pragma unroll
    for (int tt = 0; tt < 2; ++tt)
        #pragma unroll
        for (int ks = 0; ks < 16; ++ks) {
            union { uint4 u; short8 s; } cv;
            cv.u = eF[((w * 2 + tt) * 16 + ks) * 64 + l];
            A[tt][ks] = cv.s;
        }

    for (int bi = 0; bi < 4; ++bi) {
        const int b = blockIdx.x * 4 + bi;

        __syncthreads();   // previous batch done reading Cb
        float4 z4 = make_float4(0.f, 0.f, 0.f, 0.f);
        for (int idx = t; idx < (12 * CSTF) / 4; idx += 256)
            ((float4*)U)[idx] = z4;
        ((int2*)xb)[t] = ((const int2*)(x + b * IN_N))[t];
        __syncthreads();

        // scatter: C[h][x[b,i]] += w[h][i]
        #pragma unroll
        for (int k = 0; k < 2; ++k) {
            int r = xb[t + k * 256];
            #pragma unroll
            for (int h = 0; h < 12; ++h)
                atomicAdd(&U[h * CSTF + r], wv[k][h]);
        }
        __syncthreads();

        // cvt f32 -> bf16 in place (regs + barrier)
        float tmp[24];
        #pragma unroll
        for (int h = 0; h < 12; ++h) {
            tmp[2 * h]     = U[h * CSTF + t];
            tmp[2 * h + 1] = U[h * CSTF + 256 + t];
        }
        __syncthreads();
        #pragma unroll
        for (int h = 0; h < 12; ++h) {
            Cb[h * CSTB + t]       = f2bf(tmp[2 * h]);
            Cb[h * CSTB + 256 + t] = f2bf(tmp[2 * h + 1]);
        }
        __syncthreads();
        // Cb rows 12..15 unwritten: only feed D cols >=12 which are zeroed.

        // MFMA: 16 B-frag reads, each used by both tiles
        f32x4 acc0 = {0.f, 0.f, 0.f, 0.f}, acc1 = {0.f, 0.f, 0.f, 0.f};
        #pragma unroll
        for (int ks = 0; ks < 16; ++ks) {
            union { uint4 u; short8 s; } bv;
            bv.u = *(const uint4*)&Cb[h16 * CSTB + ks * 32 + quad * 8];
            acc0 = __builtin_amdgcn_mfma_f32_16x16x32_bf16(A[0][ks], bv.s, acc0, 0, 0, 0);
            acc1 = __builtin_amdgcn_mfma_f32_16x16x32_bf16(A[1][ks], bv.s, acc1, 0, 0, 0);
        }

        // store [b][s][h16]: 2-B lanes, pads (h16>=12) zeroed -> full records
        #pragma unroll
        for (int tt = 0; tt < 2; ++tt) {
            const f32x4 acc = tt ? acc1 : acc0;
            #pragma unroll
            for (int r = 0; r < 4; ++r) {
                int s = (w * 2 + tt) * 16 + quad * 4 + r;
                ushort val = (h16 < HID_N) ? f2bf(acc[r]) : (ushort)0;
                preB[((size_t)b * SEQ_N + s) * HP_N + h16] = val;
            }
        }
    }
}

// ---------------------------------------------------------------------------
// k_rev: rev[b][h] = tanh( sum_i emb[x[b,i],127]*w_ih_r[h,i] + b_ih_r + b_hh_r )
// One wave per b (4 b per 256-thr block).
// ---------------------------------------------------------------------------
__global__ __launch_bounds__(256) void k_rev(
    const int* __restrict__ x, const float* __restrict__ emb,
    const float* __restrict__ w_ih_r,
    const float* __restrict__ b_ih_r, const float* __restrict__ b_hh_r,
    float* __restrict__ rev)
{
    const int b = blockIdx.x * 4 + (threadIdx.x >> 6);
    const int l = threadIdx.x & 63;

    float p[12];
    #pragma unroll
    for (int h = 0; h < 12; ++h) p[h] = 0.f;

    for (int k = 0; k < 8; ++k) {
        int i = l + k * 64;
        int r = x[b * IN_N + i];
        float ev = emb[r * SEQ_N + 127];
        #pragma unroll
        for (int h = 0; h < 12; ++h)
            p[h] = __builtin_fmaf(ev, w_ih_r[h * IN_N + i], p[h]);
    }
    #pragma unroll
    for (int off = 32; off; off >>= 1) {
        #pragma unroll
        for (int h = 0; h < 12; ++h) p[h] += __shfl_xor(p[h], off);
    }
    if (l == 0) {
        #pragma unroll
        for (int h = 0; h < 12; ++h)
            rev[b * HP_N + h] = fast_tanh(p[h] + b_ih_r[h] + b_hh_r[h]);
        #pragma unroll
        for (int h = 12; h < 16; ++h) rev[b * HP_N + h] = 0.f;
    }
}

// ---------------------------------------------------------------------------
// k_scan v2: 4 lanes per batch (quad), lane q owns h_{q,q+4,q+8}.
// Cross-lane h exchange via DPP quad-broadcast (VALU latency, no LDS pipe).
// 128 blocks x 64 thr = 8192 lanes = 2048 batches.
// ---------------------------------------------------------------------------
__global__ __launch_bounds__(64) void k_scan(
    const ushort* __restrict__ preB, const float* __restrict__ rev,
    const float* __restrict__ w_hh_f,
    const float* __restrict__ b_ih_f, const float* __restrict__ b_hh_f,
    const float* __restrict__ fc_w, const float* __restrict__ fc_b,
    float* __restrict__ out)
{
    const int l = threadIdx.x;
    const int q = l & 3;
    const int b = blockIdx.x * 16 + (l >> 2);

    // per-lane W rows (q, q+4, q+8) and biases
    float W[3][12], bias[3];
    #pragma unroll
    for (int r = 0; r < 3; ++r) {
        int j = q + 4 * r;
        #pragma unroll
        for (int k = 0; k < 12; ++k) W[r][k] = w_hh_f[j * 12 + k];
        bias[r] = b_ih_f[j] + b_hh_f[j];
    }

    const ushort* pb = preB + (size_t)b * SEQ_N * HP_N;
    const uint4* p4 = (const uint4*)pb;   // record s -> p4[2s] = h0..h7
    const uint2* p2 = (const uint2*)pb;   // record s -> p2[4s+2] = h8..h11

    const int qh = q >> 1;                // which uint within pair
    const int sh = (q & 1) ? 0 : 16;      // bf16 extract shift

    float hreg[3] = {0.f, 0.f, 0.f};      // h_{q}, h_{q+4}, h_{q+8}

    uint4 a4 = p4[0], b4 = p4[2];
    uint2 a2 = p2[2], b2 = p2[6];

    for (int s = 0; s < SEQ_N; s += 2) {
        // prefetch s+2, s+3
        int sn0 = (s + 2) & 127, sn1 = (s + 3) & 127;
        uint4 n4 = p4[2 * sn0], m4 = p4[2 * sn1];
        uint2 n2 = p2[4 * sn0 + 2], m2 = p2[4 * sn1 + 2];

        #pragma unroll
        for (int half = 0; half < 2; ++half) {
            const uint4 c4 = half ? b4 : a4;
            const uint2 c2 = half ? b2 : a2;

            // gather previous h (12 values) via DPP quad-broadcast
            float hk[12];
            qgather(hreg[0], hk);
            qgather(hreg[1], hk + 4);
            qgather(hreg[2], hk + 8);

            // unpack this lane's 3 pre values
            uint u0 = qh ? c4.y : c4.x;
            uint u1 = qh ? c4.w : c4.z;
            uint u2v = qh ? c2.y : c2.x;
            float p0 = __uint_as_float((u0 << sh) & 0xffff0000u) + bias[0];
            float p1 = __uint_as_float((u1 << sh) & 0xffff0000u) + bias[1];
            float p2v = __uint_as_float((u2v << sh) & 0xffff0000u) + bias[2];

            #pragma unroll
            for (int k = 0; k < 12; ++k) {
                p0  = __builtin_fmaf(W[0][k], hk[k], p0);
                p1  = __builtin_fmaf(W[1][k], hk[k], p1);
                p2v = __builtin_fmaf(W[2][k], hk[k], p2v);
            }
            hreg[0] = fast_tanh(p0);
            hreg[1] = fast_tanh(p1);
            hreg[2] = fast_tanh(p2v);
        }
        a4 = n4; a2 = n2; b4 = m4; b2 = m2;
    }

    // final gather of h_T into all lanes
    float hk[12];
    qgather(hreg[0], hk);
    qgather(hreg[1], hk + 4);
    qgather(hreg[2], hk + 8);

    // FC epilogue: lane q (<3) computes output o=q
    if (q < OUT_N) {
        const float* fw = fc_w + q * 24;
        float o = fc_b[q];
        #pragma unroll
        for (int k = 0; k < 12; ++k)
            o += fw[k] * hk[k] + fw[12 + k] * rev[b * HP_N + k];
        out[b * OUT_N + q] = o;
    }
}

// ---------------------------------------------------------------------------
extern "C" void kernel_launch(void* const* d_in, const int* in_sizes, int n_in,
                              void* d_out, int out_size, void* d_ws, size_t ws_size,
                              hipStream_t stream) {
    const int*   x      = (const int*)  d_in[0];
    const float* emb    = (const float*)d_in[1];
    const float* w_ih_f = (const float*)d_in[2];
    const float* w_hh_f = (const float*)d_in[3];
    const float* b_ih_f = (const float*)d_in[4];
    const float* b_hh_f = (const float*)d_in[5];
    const float* w_ih_r = (const float*)d_in[6];
    const float* b_ih_r = (const float*)d_in[8];
    const float* b_hh_r = (const float*)d_in[9];
    const float* fc_w   = (const float*)d_in[10];
    const float* fc_b   = (const float*)d_in[11];
    float* out = (float*)d_out;

    ushort* preB = (ushort*)d_ws;                       // [2048][128][16] bf16 = 8 MB
    float*  rev  = (float*)((char*)d_ws + 8388608);     // 128 KB
    ushort* embF = (ushort*)((char*)d_ws + 8519680);    // 128 KB

    k_prep<<<128,      64, 0, stream>>>(emb, embF);
    k_pre <<<B_N / 4, 256, 0, stream>>>(x, embF, w_ih_f, preB);
    k_rev <<<B_N / 4, 256, 0, stream>>>(x, emb, w_ih_r, b_ih_r, b_hh_r, rev);
    k_scan<<<B_N / 16, 64, 0, stream>>>(preB, rev, w_hh_f, b_ih_f, b_hh_f,
                                        fc_w, fc_b, out);
}